// Round 7
// baseline (100.152 us; speedup 1.0000x reference)
//
#include <hip/hip_runtime.h>
#include <hip/hip_bf16.h>

#define PAD_IDX 1

typedef short  short8  __attribute__((ext_vector_type(8)));
typedef float  f32x16  __attribute__((ext_vector_type(16)));
typedef float  f32x4   __attribute__((ext_vector_type(4)));

#define SLABW 112   // max chunk width; slab = 32 x SLABW (14.3 KB) -> 8 blocks/CU

static __device__ __forceinline__ ushort f2bf(float f) {
    union { float f; unsigned u; } v; v.f = f;
    unsigned u = v.u;
    u += 0x7fffu + ((u >> 16) & 1u);      // round-to-nearest-even
    return (ushort)(u >> 16);
}

// =====================================================================
// Kernel 1: gather + pad-mask + L2-normalize + bf16 cast.
// ws rows: [0,D) = doc embeddings, [D, D+Lq) = query embeddings. 64 bf16/row.
// =====================================================================
__global__ __launch_bounds__(256) void lm_prep(
    const float* __restrict__ embed,
    const int*   __restrict__ quer,
    const int*   __restrict__ doc,
    ushort*      __restrict__ ws,
    int Lq, int D)
{
    const int t    = blockIdx.x * 256 + threadIdx.x;
    const int r    = t >> 2;
    const int part = t & 3;
    if (r >= D + Lq) return;

    const int id = (r < D) ? doc[r] : quer[r - D];
    const float* rowp = embed + (size_t)id * 64 + part * 16;

    float v[16];
    #pragma unroll
    for (int c = 0; c < 4; ++c) {
        float4 f = ((const float4*)rowp)[c];
        v[c*4+0] = f.x; v[c*4+1] = f.y; v[c*4+2] = f.z; v[c*4+3] = f.w;
    }
    float s = 0.f;
    #pragma unroll
    for (int c = 0; c < 16; ++c) s += v[c] * v[c];
    s += __shfl_xor(s, 1);
    s += __shfl_xor(s, 2);
    const float inv = (id != PAD_IDX && s > 0.f) ? rsqrtf(s) : 0.f;

    unsigned pk[8];
    #pragma unroll
    for (int c = 0; c < 8; ++c) {
        const ushort lo = f2bf(v[2*c]   * inv);
        const ushort hi = f2bf(v[2*c+1] * inv);
        pk[c] = (unsigned)lo | ((unsigned)hi << 16);
    }
    ushort* dst = ws + (size_t)r * 64 + part * 16;
    ((uint4*)dst)[0] = make_uint4(pk[0], pk[1], pk[2], pk[3]);
    ((uint4*)dst)[1] = make_uint4(pk[4], pk[5], pk[6], pk[7]);
}

// =====================================================================
// Kernel 2: MFMA main with LDS-staged output-linear epilogue.
// Unit = (para p, q-tile qt of 128). 4 waves: (qw,dw) in 2x2, each wave
// 64q x 64d = 2x2 frags of 32x32x16 bf16, operands straight from ws.
// Epilogue: 4 phases of 32 q-rows; phase ph -> (qw,mi)=(ph>>1, ph&1).
// acc -> LDS slab [row][s] (stride w) == output layout, then a linear
// LDS->global nontemporal f32x4 stream; xor inline from cached ids.
// Slab 32xSLABW (15.4 KB total LDS) -> 8 blocks/CU.
// =====================================================================
__global__ __launch_bounds__(256) void lm_mfma(
    const ushort* __restrict__ ws,
    const int*    __restrict__ quer,
    const int*    __restrict__ doc,
    const int*    __restrict__ para,
    float*        __restrict__ out,
    int Lq, int D, int qtiles)
{
    __shared__ float slab[32 * SLABW];
    __shared__ int   qid_s[128];
    __shared__ int   did_s[128];

    const int ps       = para[0];
    const int num_para = D / ps;
    const long long total = (long long)num_para * qtiles;
    const size_t cos_off  = (size_t)num_para * (size_t)Lq * (size_t)ps;

    const int tid  = threadIdx.x;
    const int wv   = tid >> 6;
    const int lane = tid & 63;
    const int qw   = wv >> 1;
    const int dw   = wv & 1;
    const int ln   = lane & 31;
    const int h    = lane >> 5;
    const ushort* wsQ = ws + (size_t)D * 64;

    // bijective XCD swizzle params over [0,total)
    const long long xq = total >> 3;
    const int       xr = (int)(total & 7);

    for (long long u0 = blockIdx.x; u0 < total; u0 += gridDim.x) {
        const int       xcd = (int)(u0 & 7);
        const long long i8  = u0 >> 3;
        const long long u   = (xcd < xr ? (long long)xcd * (xq + 1) + i8
                                        : (long long)xr * (xq + 1) + (long long)(xcd - xr) * xq + i8);

        const int p  = (int)(u / qtiles);
        const int qt = (int)(u - (long long)p * qtiles);
        const int q_base = qt * 128;
        const size_t pbase = (size_t)p * (size_t)Lq * (size_t)ps;

        for (int sb = 0; sb < ps; sb += SLABW) {
            const int w = (ps - sb < SLABW) ? (ps - sb) : SLABW;

            __syncthreads();   // protect slab/ids from previous chunk's readers

            // ---- stage ids ----
            if (tid < w)   did_s[tid] = doc[p * ps + sb + tid];
            if (tid < 128) {
                const int qg = q_base + tid;
                qid_s[tid] = (qg < Lq) ? quer[qg] : PAD_IDX;
            }

            // ---- accumulators ----
            f32x16 acc[2][2];
            #pragma unroll
            for (int mi = 0; mi < 2; ++mi)
                #pragma unroll
                for (int ni = 0; ni < 2; ++ni)
                    #pragma unroll
                    for (int e = 0; e < 16; ++e) acc[mi][ni][e] = 0.f;

            // ---- fragment pointers (16B/lane contiguous from ws) ----
            const short8* ap[2];
            const short8* bp[2];
            #pragma unroll
            for (int mi = 0; mi < 2; ++mi) {
                int qr = q_base + qw * 64 + mi * 32 + ln;
                if (qr > Lq - 1) qr = Lq - 1;
                ap[mi] = (const short8*)(wsQ + (size_t)qr * 64 + h * 8);
            }
            #pragma unroll
            for (int ni = 0; ni < 2; ++ni) {
                const int s = sb + dw * 64 + ni * 32 + ln;
                int dr = p * ps + s;
                if (dr > D - 1) dr = D - 1;
                bp[ni] = (const short8*)(ws + (size_t)dr * 64 + h * 8);
            }

            // ---- K loop ----
            #pragma unroll
            for (int ks = 0; ks < 4; ++ks) {
                const short8 a0 = ap[0][2 * ks];
                const short8 a1 = ap[1][2 * ks];
                const short8 b0 = bp[0][2 * ks];
                const short8 b1 = bp[1][2 * ks];
                acc[0][0] = __builtin_amdgcn_mfma_f32_32x32x16_bf16(a0, b0, acc[0][0], 0, 0, 0);
                acc[0][1] = __builtin_amdgcn_mfma_f32_32x32x16_bf16(a0, b1, acc[0][1], 0, 0, 0);
                acc[1][0] = __builtin_amdgcn_mfma_f32_32x32x16_bf16(a1, b0, acc[1][0], 0, 0, 0);
                acc[1][1] = __builtin_amdgcn_mfma_f32_32x32x16_bf16(a1, b1, acc[1][1], 0, 0, 0);
            }

            // ---- 4-phase epilogue: 32 q-rows per phase through slab ----
            #pragma unroll
            for (int ph = 0; ph < 4; ++ph) {
                __syncthreads();
                if (qw == (ph >> 1)) {
                    const int mi = ph & 1;
                    #pragma unroll
                    for (int r = 0; r < 16; ++r) {
                        const int row = (r & 3) + 8 * (r >> 2) + 4 * h;   // 0..31
                        #pragma unroll
                        for (int ni = 0; ni < 2; ++ni) {
                            const int s = dw * 64 + ni * 32 + ln;
                            if (s < w) slab[row * w + s] = acc[mi][ni][r];
                        }
                    }
                }
                __syncthreads();

                int nrow = Lq - (q_base + ph * 32);
                if (nrow > 32) nrow = 32;
                if (nrow <= 0) continue;

                const size_t gbase = pbase + (size_t)(q_base + ph * 32) * ps + sb;

                if ((w & 3) == 0) {
                    const int psq   = w >> 2;           // float4s per row
                    const int n4    = nrow * psq;
                    const int stepL = 256 / psq;
                    const int stepS = 256 % psq;
                    int lr = tid / psq;
                    int s4 = tid - lr * psq;
                    for (int i = tid; i < n4; i += 256) {
                        const f32x4 c = *(const f32x4*)&slab[i * 4];
                        const int s = s4 * 4;
                        const int qi = qid_s[ph * 32 + lr];
                        f32x4 x;
                        x.x = (qi == did_s[s + 0]) ? 1.f : 0.f;
                        x.y = (qi == did_s[s + 1]) ? 1.f : 0.f;
                        x.z = (qi == did_s[s + 2]) ? 1.f : 0.f;
                        x.w = (qi == did_s[s + 3]) ? 1.f : 0.f;
                        const size_t idx = gbase + (size_t)lr * ps + s;
                        __builtin_nontemporal_store(x, (f32x4*)(out + idx));
                        __builtin_nontemporal_store(c, (f32x4*)(out + cos_off + idx));
                        lr += stepL; s4 += stepS;
                        if (s4 >= psq) { s4 -= psq; ++lr; }
                    }
                } else {
                    const int n = nrow * w;
                    for (int i = tid; i < n; i += 256) {
                        const int lr = i / w;
                        const int s  = i - lr * w;
                        const float c = slab[i];
                        const int qi  = qid_s[ph * 32 + lr];
                        const size_t idx = gbase + (size_t)lr * ps + s;
                        __builtin_nontemporal_store((qi == did_s[s]) ? 1.f : 0.f, out + idx);
                        __builtin_nontemporal_store(c, out + cos_off + idx);
                    }
                }
            }
        }
    }
}

// =====================================================================
// Fallback (round-1 fp32 kernel) if ws is too small for the bf16 matrix.
// =====================================================================
__global__ __launch_bounds__(256) void lm_main(
    const float* __restrict__ embed,
    const int* __restrict__ quer,
    const int* __restrict__ doc,
    const int* __restrict__ para,
    float* __restrict__ out,
    int Lq, int D)
{
    const int E  = 64;
    const int QS = 68, DS = 132;

    __shared__ float As[64 * 68];
    __shared__ float Bs[64 * 132];
    __shared__ int   qid_s[64];
    __shared__ int   did_s[128];

    const int tid    = threadIdx.x;
    const int d_base = blockIdx.x * 128;
    const int q_base = blockIdx.y * 64;

    {
        const int r    = tid >> 2;
        const int part = tid & 3;
        const int qg   = q_base + r;
        const int qid  = (qg < Lq) ? quer[qg] : PAD_IDX;
        const float* rowp = embed + (size_t)qid * E + part * 16;
        float v[16];
        #pragma unroll
        for (int c = 0; c < 4; ++c) {
            float4 f = ((const float4*)rowp)[c];
            v[c*4+0] = f.x; v[c*4+1] = f.y; v[c*4+2] = f.z; v[c*4+3] = f.w;
        }
        float s = 0.f;
        #pragma unroll
        for (int c = 0; c < 16; ++c) s += v[c] * v[c];
        s += __shfl_xor(s, 1);
        s += __shfl_xor(s, 2);
        const float inv = (qid != PAD_IDX && qg < Lq && s > 0.f) ? rsqrtf(s) : 0.f;
        #pragma unroll
        for (int c = 0; c < 16; ++c)
            As[(part * 16 + c) * QS + r] = v[c] * inv;
        if (part == 0) qid_s[r] = qid;
    }
    {
        const int r    = tid >> 1;
        const int half = tid & 1;
        const int dg   = d_base + r;
        const int did  = (dg < D) ? doc[dg] : PAD_IDX;
        const float* rowp = embed + (size_t)did * E + half * 32;
        float v[32];
        #pragma unroll
        for (int c = 0; c < 8; ++c) {
            float4 f = ((const float4*)rowp)[c];
            v[c*4+0] = f.x; v[c*4+1] = f.y; v[c*4+2] = f.z; v[c*4+3] = f.w;
        }
        float s = 0.f;
        #pragma unroll
        for (int c = 0; c < 32; ++c) s += v[c] * v[c];
        s += __shfl_xor(s, 1);
        const float inv = (dg < D && did != PAD_IDX && s > 0.f) ? rsqrtf(s) : 0.f;
        #pragma unroll
        for (int c = 0; c < 32; ++c)
            Bs[(half * 32 + c) * DS + r] = v[c] * inv;
        if (half == 0) did_s[r] = did;
    }

    __syncthreads();

    const int tq = tid >> 4;
    const int td = tid & 15;
    float acc[4][8];
    #pragma unroll
    for (int i = 0; i < 4; ++i)
        #pragma unroll
        for (int j = 0; j < 8; ++j) acc[i][j] = 0.f;

    #pragma unroll 8
    for (int k = 0; k < E; ++k) {
        const float4 a  = *(const float4*)&As[k * QS + tq * 4];
        const float4 b0 = *(const float4*)&Bs[k * DS + td * 8];
        const float4 b1 = *(const float4*)&Bs[k * DS + td * 8 + 4];
        const float av[4] = {a.x, a.y, a.z, a.w};
        const float bv[8] = {b0.x, b0.y, b0.z, b0.w, b1.x, b1.y, b1.z, b1.w};
        #pragma unroll
        for (int i = 0; i < 4; ++i)
            #pragma unroll
            for (int j = 0; j < 8; ++j)
                acc[i][j] = fmaf(av[i], bv[j], acc[i][j]);
    }

    const int ps        = para[0];
    const int rowstride = Lq * ps;
    const size_t cos_off = (size_t)(D / ps) * (size_t)Lq * (size_t)ps;

    #pragma unroll
    for (int i = 0; i < 4; ++i) {
        const int q  = q_base + tq * 4 + i;
        if (q >= Lq) continue;
        const int qi = qid_s[tq * 4 + i];
        const int d0 = d_base + td * 8;
        int p = d0 / ps;
        int s = d0 - p * ps;
        #pragma unroll
        for (int j = 0; j < 8; ++j) {
            const int d = d0 + j;
            if (d < D && p < D / ps) {
                const size_t idx = (size_t)p * rowstride + (size_t)q * ps + s;
                out[idx]           = (qi == did_s[td * 8 + j]) ? 1.0f : 0.0f;
                out[cos_off + idx] = acc[i][j];
            }
            if (++s == ps) { s = 0; ++p; }
        }
    }
}

extern "C" void kernel_launch(void* const* d_in, const int* in_sizes, int n_in,
                              void* d_out, int out_size, void* d_ws, size_t ws_size,
                              hipStream_t stream) {
    const float* embed = (const float*)d_in[0];
    const int*   quer  = (const int*)d_in[1];
    const int*   doc   = (const int*)d_in[2];
    const int*   para  = (const int*)d_in[3];
    float*       out   = (float*)d_out;

    const int Lq = in_sizes[1];      // 512
    const int D  = in_sizes[2];      // 100000

    const size_t need = (size_t)(D + Lq) * 64 * sizeof(ushort);
    if (ws_size >= need) {
        ushort* ws = (ushort*)d_ws;
        const int prepBlocks = ((D + Lq) * 4 + 255) / 256;
        lm_prep<<<prepBlocks, 256, 0, stream>>>(embed, quer, doc, ws, Lq, D);
        const int qtiles = (Lq + 127) / 128;
        lm_mfma<<<4096, 256, 0, stream>>>(ws, quer, doc, para, out, Lq, D, qtiles);
    } else {
        const int qBlocks = (Lq + 63) / 64;
        const int dBlocks = (D + 127) / 128;
        dim3 grid(dBlocks, qBlocks);
        lm_main<<<grid, 256, 0, stream>>>(embed, quer, doc, para, out, Lq, D);
    }
}

// Round 8
// 97.397 us; speedup vs baseline: 1.0283x; 1.0283x over previous
//
#include <hip/hip_runtime.h>
#include <hip/hip_bf16.h>

#define PAD_IDX 1

typedef short  short8  __attribute__((ext_vector_type(8)));
typedef float  f32x16  __attribute__((ext_vector_type(16)));
typedef float  f32x4   __attribute__((ext_vector_type(4)));

#define SLABW 112   // slab column capacity == max chunk width (29.7 KB LDS -> 5 blocks/CU)

static __device__ __forceinline__ ushort f2bf(float f) {
    union { float f; unsigned u; } v; v.f = f;
    unsigned u = v.u;
    u += 0x7fffu + ((u >> 16) & 1u);      // round-to-nearest-even
    return (ushort)(u >> 16);
}

// =====================================================================
// Kernel 1: gather + pad-mask + L2-normalize + bf16 cast.
// ws rows: [0,D) = doc embeddings, [D, D+Lq) = query embeddings. 64 bf16/row.
// =====================================================================
__global__ __launch_bounds__(256) void lm_prep(
    const float* __restrict__ embed,
    const int*   __restrict__ quer,
    const int*   __restrict__ doc,
    ushort*      __restrict__ ws,
    int Lq, int D)
{
    const int t    = blockIdx.x * 256 + threadIdx.x;
    const int r    = t >> 2;
    const int part = t & 3;
    if (r >= D + Lq) return;

    const int id = (r < D) ? doc[r] : quer[r - D];
    const float* rowp = embed + (size_t)id * 64 + part * 16;

    float v[16];
    #pragma unroll
    for (int c = 0; c < 4; ++c) {
        float4 f = ((const float4*)rowp)[c];
        v[c*4+0] = f.x; v[c*4+1] = f.y; v[c*4+2] = f.z; v[c*4+3] = f.w;
    }
    float s = 0.f;
    #pragma unroll
    for (int c = 0; c < 16; ++c) s += v[c] * v[c];
    s += __shfl_xor(s, 1);
    s += __shfl_xor(s, 2);
    const float inv = (id != PAD_IDX && s > 0.f) ? rsqrtf(s) : 0.f;

    unsigned pk[8];
    #pragma unroll
    for (int c = 0; c < 8; ++c) {
        const ushort lo = f2bf(v[2*c]   * inv);
        const ushort hi = f2bf(v[2*c+1] * inv);
        pk[c] = (unsigned)lo | ((unsigned)hi << 16);
    }
    ushort* dst = ws + (size_t)r * 64 + part * 16;
    ((uint4*)dst)[0] = make_uint4(pk[0], pk[1], pk[2], pk[3]);
    ((uint4*)dst)[1] = make_uint4(pk[4], pk[5], pk[6], pk[7]);
}

// =====================================================================
// Kernel 2: MFMA main with LDS-staged output-linear epilogue.
// Unit = (para p, q-tile qt of 128). 4 waves: (qw,dw) in 2x2, each wave
// 64q x 64d = 2x2 frags of 32x32x16 bf16, operands straight from ws.
// Chunk width capped at SLABW so the slab path always applies.
// Epilogue: 2 phases of 64 q-rows; acc -> LDS slab [row][s] (stride w)
// == output layout, then a linear LDS->global nontemporal f32x4 stream;
// xor inline from cached ids.
// =====================================================================
__global__ __launch_bounds__(256) void lm_mfma(
    const ushort* __restrict__ ws,
    const int*    __restrict__ quer,
    const int*    __restrict__ doc,
    const int*    __restrict__ para,
    float*        __restrict__ out,
    int Lq, int D, int qtiles)
{
    __shared__ float slab[64 * SLABW];
    __shared__ int   qid_s[128];
    __shared__ int   did_s[128];

    const int ps       = para[0];
    const int num_para = D / ps;
    const long long total = (long long)num_para * qtiles;
    const size_t cos_off  = (size_t)num_para * (size_t)Lq * (size_t)ps;

    const int tid  = threadIdx.x;
    const int wv   = tid >> 6;
    const int lane = tid & 63;
    const int qw   = wv >> 1;
    const int dw   = wv & 1;
    const int ln   = lane & 31;
    const int h    = lane >> 5;
    const ushort* wsQ = ws + (size_t)D * 64;

    // bijective XCD swizzle params over [0,total)
    const long long xq = total >> 3;
    const int       xr = (int)(total & 7);

    for (long long u0 = blockIdx.x; u0 < total; u0 += gridDim.x) {
        const int       xcd = (int)(u0 & 7);
        const long long i8  = u0 >> 3;
        const long long u   = (xcd < xr ? (long long)xcd * (xq + 1) + i8
                                        : (long long)xr * (xq + 1) + (long long)(xcd - xr) * xq + i8);

        const int p  = (int)(u / qtiles);
        const int qt = (int)(u - (long long)p * qtiles);
        const int q_base = qt * 128;
        const size_t pbase = (size_t)p * (size_t)Lq * (size_t)ps;

        for (int sb = 0; sb < ps; sb += SLABW) {
            const int w = (ps - sb < SLABW) ? (ps - sb) : SLABW;

            __syncthreads();   // protect slab/ids from previous chunk's readers

            // ---- stage ids ----
            if (tid < w)   did_s[tid] = doc[p * ps + sb + tid];
            if (tid < 128) {
                const int qg = q_base + tid;
                qid_s[tid] = (qg < Lq) ? quer[qg] : PAD_IDX;
            }

            // ---- accumulators ----
            f32x16 acc[2][2];
            #pragma unroll
            for (int mi = 0; mi < 2; ++mi)
                #pragma unroll
                for (int ni = 0; ni < 2; ++ni)
                    #pragma unroll
                    for (int e = 0; e < 16; ++e) acc[mi][ni][e] = 0.f;

            // ---- fragment pointers (16B/lane contiguous from ws) ----
            const short8* ap[2];
            const short8* bp[2];
            #pragma unroll
            for (int mi = 0; mi < 2; ++mi) {
                int qr = q_base + qw * 64 + mi * 32 + ln;
                if (qr > Lq - 1) qr = Lq - 1;
                ap[mi] = (const short8*)(wsQ + (size_t)qr * 64 + h * 8);
            }
            #pragma unroll
            for (int ni = 0; ni < 2; ++ni) {
                const int s = sb + dw * 64 + ni * 32 + ln;
                int dr = p * ps + s;
                if (dr > D - 1) dr = D - 1;
                bp[ni] = (const short8*)(ws + (size_t)dr * 64 + h * 8);
            }

            // ---- K loop ----
            #pragma unroll
            for (int ks = 0; ks < 4; ++ks) {
                const short8 a0 = ap[0][2 * ks];
                const short8 a1 = ap[1][2 * ks];
                const short8 b0 = bp[0][2 * ks];
                const short8 b1 = bp[1][2 * ks];
                acc[0][0] = __builtin_amdgcn_mfma_f32_32x32x16_bf16(a0, b0, acc[0][0], 0, 0, 0);
                acc[0][1] = __builtin_amdgcn_mfma_f32_32x32x16_bf16(a0, b1, acc[0][1], 0, 0, 0);
                acc[1][0] = __builtin_amdgcn_mfma_f32_32x32x16_bf16(a1, b0, acc[1][0], 0, 0, 0);
                acc[1][1] = __builtin_amdgcn_mfma_f32_32x32x16_bf16(a1, b1, acc[1][1], 0, 0, 0);
            }

            // ---- 2-phase epilogue: 64 q-rows per phase through slab ----
            #pragma unroll
            for (int ph = 0; ph < 2; ++ph) {
                __syncthreads();
                if (qw == ph) {
                    #pragma unroll
                    for (int mi = 0; mi < 2; ++mi) {
                        #pragma unroll
                        for (int r = 0; r < 16; ++r) {
                            const int row = mi * 32 + (r & 3) + 8 * (r >> 2) + 4 * h;
                            #pragma unroll
                            for (int ni = 0; ni < 2; ++ni) {
                                const int s = dw * 64 + ni * 32 + ln;
                                if (s < w) slab[row * w + s] = acc[mi][ni][r];
                            }
                        }
                    }
                }
                __syncthreads();

                int nrow = Lq - (q_base + ph * 64);
                if (nrow > 64) nrow = 64;
                if (nrow <= 0) continue;

                const size_t gbase = pbase + (size_t)(q_base + ph * 64) * ps + sb;

                if ((w & 3) == 0) {
                    const int psq   = w >> 2;           // float4s per row
                    const int n4    = nrow * psq;
                    const int stepL = 256 / psq;
                    const int stepS = 256 % psq;
                    int lr = tid / psq;
                    int s4 = tid - lr * psq;
                    for (int i = tid; i < n4; i += 256) {
                        const f32x4 c = *(const f32x4*)&slab[i * 4];
                        const int s = s4 * 4;
                        const int qi = qid_s[ph * 64 + lr];
                        f32x4 x;
                        x.x = (qi == did_s[s + 0]) ? 1.f : 0.f;
                        x.y = (qi == did_s[s + 1]) ? 1.f : 0.f;
                        x.z = (qi == did_s[s + 2]) ? 1.f : 0.f;
                        x.w = (qi == did_s[s + 3]) ? 1.f : 0.f;
                        const size_t idx = gbase + (size_t)lr * ps + s;
                        __builtin_nontemporal_store(x, (f32x4*)(out + idx));
                        __builtin_nontemporal_store(c, (f32x4*)(out + cos_off + idx));
                        lr += stepL; s4 += stepS;
                        if (s4 >= psq) { s4 -= psq; ++lr; }
                    }
                } else {
                    const int n = nrow * w;
                    for (int i = tid; i < n; i += 256) {
                        const int lr = i / w;
                        const int s  = i - lr * w;
                        const float c = slab[i];
                        const int qi  = qid_s[ph * 64 + lr];
                        const size_t idx = gbase + (size_t)lr * ps + s;
                        __builtin_nontemporal_store((qi == did_s[s]) ? 1.f : 0.f, out + idx);
                        __builtin_nontemporal_store(c, out + cos_off + idx);
                    }
                }
            }
        }
    }
}

// =====================================================================
// Fallback (round-1 fp32 kernel) if ws is too small for the bf16 matrix.
// =====================================================================
__global__ __launch_bounds__(256) void lm_main(
    const float* __restrict__ embed,
    const int* __restrict__ quer,
    const int* __restrict__ doc,
    const int* __restrict__ para,
    float* __restrict__ out,
    int Lq, int D)
{
    const int E  = 64;
    const int QS = 68, DS = 132;

    __shared__ float As[64 * 68];
    __shared__ float Bs[64 * 132];
    __shared__ int   qid_s[64];
    __shared__ int   did_s[128];

    const int tid    = threadIdx.x;
    const int d_base = blockIdx.x * 128;
    const int q_base = blockIdx.y * 64;

    {
        const int r    = tid >> 2;
        const int part = tid & 3;
        const int qg   = q_base + r;
        const int qid  = (qg < Lq) ? quer[qg] : PAD_IDX;
        const float* rowp = embed + (size_t)qid * E + part * 16;
        float v[16];
        #pragma unroll
        for (int c = 0; c < 4; ++c) {
            float4 f = ((const float4*)rowp)[c];
            v[c*4+0] = f.x; v[c*4+1] = f.y; v[c*4+2] = f.z; v[c*4+3] = f.w;
        }
        float s = 0.f;
        #pragma unroll
        for (int c = 0; c < 16; ++c) s += v[c] * v[c];
        s += __shfl_xor(s, 1);
        s += __shfl_xor(s, 2);
        const float inv = (qid != PAD_IDX && qg < Lq && s > 0.f) ? rsqrtf(s) : 0.f;
        #pragma unroll
        for (int c = 0; c < 16; ++c)
            As[(part * 16 + c) * QS + r] = v[c] * inv;
        if (part == 0) qid_s[r] = qid;
    }
    {
        const int r    = tid >> 1;
        const int half = tid & 1;
        const int dg   = d_base + r;
        const int did  = (dg < D) ? doc[dg] : PAD_IDX;
        const float* rowp = embed + (size_t)did * E + half * 32;
        float v[32];
        #pragma unroll
        for (int c = 0; c < 8; ++c) {
            float4 f = ((const float4*)rowp)[c];
            v[c*4+0] = f.x; v[c*4+1] = f.y; v[c*4+2] = f.z; v[c*4+3] = f.w;
        }
        float s = 0.f;
        #pragma unroll
        for (int c = 0; c < 32; ++c) s += v[c] * v[c];
        s += __shfl_xor(s, 1);
        const float inv = (dg < D && did != PAD_IDX && s > 0.f) ? rsqrtf(s) : 0.f;
        #pragma unroll
        for (int c = 0; c < 32; ++c)
            Bs[(half * 32 + c) * DS + r] = v[c] * inv;
        if (half == 0) did_s[r] = did;
    }

    __syncthreads();

    const int tq = tid >> 4;
    const int td = tid & 15;
    float acc[4][8];
    #pragma unroll
    for (int i = 0; i < 4; ++i)
        #pragma unroll
        for (int j = 0; j < 8; ++j) acc[i][j] = 0.f;

    #pragma unroll 8
    for (int k = 0; k < E; ++k) {
        const float4 a  = *(const float4*)&As[k * QS + tq * 4];
        const float4 b0 = *(const float4*)&Bs[k * DS + td * 8];
        const float4 b1 = *(const float4*)&Bs[k * DS + td * 8 + 4];
        const float av[4] = {a.x, a.y, a.z, a.w};
        const float bv[8] = {b0.x, b0.y, b0.z, b0.w, b1.x, b1.y, b1.z, b1.w};
        #pragma unroll
        for (int i = 0; i < 4; ++i)
            #pragma unroll
            for (int j = 0; j < 8; ++j)
                acc[i][j] = fmaf(av[i], bv[j], acc[i][j]);
    }

    const int ps        = para[0];
    const int rowstride = Lq * ps;
    const size_t cos_off = (size_t)(D / ps) * (size_t)Lq * (size_t)ps;

    #pragma unroll
    for (int i = 0; i < 4; ++i) {
        const int q  = q_base + tq * 4 + i;
        if (q >= Lq) continue;
        const int qi = qid_s[tq * 4 + i];
        const int d0 = d_base + td * 8;
        int p = d0 / ps;
        int s = d0 - p * ps;
        #pragma unroll
        for (int j = 0; j < 8; ++j) {
            const int d = d0 + j;
            if (d < D && p < D / ps) {
                const size_t idx = (size_t)p * rowstride + (size_t)q * ps + s;
                out[idx]           = (qi == did_s[td * 8 + j]) ? 1.0f : 0.0f;
                out[cos_off + idx] = acc[i][j];
            }
            if (++s == ps) { s = 0; ++p; }
        }
    }
}

extern "C" void kernel_launch(void* const* d_in, const int* in_sizes, int n_in,
                              void* d_out, int out_size, void* d_ws, size_t ws_size,
                              hipStream_t stream) {
    const float* embed = (const float*)d_in[0];
    const int*   quer  = (const int*)d_in[1];
    const int*   doc   = (const int*)d_in[2];
    const int*   para  = (const int*)d_in[3];
    float*       out   = (float*)d_out;

    const int Lq = in_sizes[1];      // 512
    const int D  = in_sizes[2];      // 100000

    const size_t need = (size_t)(D + Lq) * 64 * sizeof(ushort);
    if (ws_size >= need) {
        ushort* ws = (ushort*)d_ws;
        const int prepBlocks = ((D + Lq) * 4 + 255) / 256;
        lm_prep<<<prepBlocks, 256, 0, stream>>>(embed, quer, doc, ws, Lq, D);
        const int qtiles = (Lq + 127) / 128;
        lm_mfma<<<4096, 256, 0, stream>>>(ws, quer, doc, para, out, Lq, D, qtiles);
    } else {
        const int qBlocks = (Lq + 63) / 64;
        const int dBlocks = (D + 127) / 128;
        dim3 grid(dBlocks, qBlocks);
        lm_main<<<grid, 256, 0, stream>>>(embed, quer, doc, para, out, Lq, D);
    }
}